// Round 5
// baseline (301.411 us; speedup 1.0000x reference)
//
#include <hip/hip_runtime.h>
#include <math.h>

// Problem constants
#define QN 4096
#define MN 65536
#define DN 384
#define CN 128
#define NCHUNK 64                 // m-chunks (grid.y of GEMM)
#define MROWS_PER_CHUNK (MN / NCHUNK)   // 1024
#define MT_PER (MROWS_PER_CHUNK / 64)   // 16 m-tiles (64 rows) per block
#define BTILE_B (64 * DN)               // 24576 B per B tile

typedef __attribute__((ext_vector_type(8))) int i32x8;
typedef __attribute__((ext_vector_type(4))) int i32x4;
typedef __attribute__((ext_vector_type(4))) float f32x4;

// f32 -> OCP e4m3fn
__device__ __forceinline__ unsigned char f2fp8(float f) {
  return (unsigned char)(__builtin_amdgcn_cvt_pk_fp8_f32(f, 0.f, 0, false) & 0xff);
}

__device__ __forceinline__ void async16(const void* g, void* l) {
  __builtin_amdgcn_global_load_lds(
      (const __attribute__((address_space(1))) unsigned int*)g,
      (__attribute__((address_space(3))) unsigned int*)l, 16, 0, 0);
}

// ------- Kernel A: L2-normalize rows (q then m) -> fp8, one wave per row ---
__global__ __launch_bounds__(256) void nrm_kernel(const float* __restrict__ qe,
                                                  const float* __restrict__ me,
                                                  unsigned char* __restrict__ yq,
                                                  unsigned char* __restrict__ ym) {
  const int row = blockIdx.x * 4 + (threadIdx.x >> 6);
  const int lane = threadIdx.x & 63;
  const float* xr;
  unsigned char* yr;
  if (row < QN) {
    xr = qe + (size_t)row * DN;
    yr = yq + (size_t)row * DN;
  } else {
    xr = me + (size_t)(row - QN) * DN;
    yr = ym + (size_t)(row - QN) * DN;
  }
  float v[6];
  float ss = 0.f;
#pragma unroll
  for (int i = 0; i < 6; ++i) {
    v[i] = xr[lane + i * 64];
    ss += v[i] * v[i];
  }
#pragma unroll
  for (int m = 1; m < 64; m <<= 1) ss += __shfl_xor(ss, m);
  const float scale = 1.0f / fmaxf(sqrtf(ss), 1e-8f);
#pragma unroll
  for (int i = 0; i < 6; ++i) yr[lane + i * 64] = f2fp8(v[i] * scale);
}

// ------- Kernel B: MX-fp8 GEMM, reg-hoisted A + double-buffered B ---------
// A (128 q-rows, full K) staged through the 48 KB LDS once, hoisted to 96
// VGPRs. Then a single-barrier pipeline over 16 B-tiles of 64 m-rows:
//   barrier; issue async B(mt+1) -> buf[!cur]; compute(mt) from buf[cur]
// The vmcnt(0) drain at each barrier lands after the loads have had a full
// compute phase in flight -> staging hidden under MFMA. XOR swizzle on 16B
// chunks (low 3 bits ^ row) keeps fragment reads 2-way/bank (free).
__global__ __launch_bounds__(256, 3) void gemm_max_kernel(
    const unsigned char* __restrict__ qn8, const unsigned char* __restrict__ mn8,
    float* __restrict__ pmax) {
  __shared__ unsigned char Bs[2 * BTILE_B];  // 48 KB (also holds A initially)
  __shared__ float smax[2][128];

  const int tid = threadIdx.x;
  const int wave = tid >> 6, lane = tid & 63;
  const int wr = wave >> 1, wc = wave & 1;   // waves: 2x2 over 128q x 64m
  const int quad = lane >> 4, l16 = lane & 15;
  const int r7 = l16 & 7;
  const int qrow0 = blockIdx.x * 128;
  const int mchunk0 = blockIdx.y * MROWS_PER_CHUNK;

  float rmax[16];
#pragma unroll
  for (int i = 0; i < 16; ++i) rmax[i] = -3.0e38f;

  // ---- stage A tile (128x384 = 48 KB) once, hoist fragments to registers --
  {
    const unsigned char* abase = qn8 + (size_t)qrow0 * DN;
#pragma unroll
    for (int i = 0; i < 12; ++i) {
      const int ci = i * 256 + tid;               // 16B chunk 0..3071
      const int row = ci / 24;
      const int j = ci - row * 24;
      const int gj = (j & 24) | ((j ^ row) & 7);  // XOR-swizzled source chunk
      async16(abase + row * DN + gj * 16, &Bs[(i * 256 + wave * 64) * 16]);
    }
  }
  __syncthreads();
  i32x8 afr[3][4];
#pragma unroll
  for (int kc = 0; kc < 3; ++kc)
#pragma unroll
    for (int rt = 0; rt < 4; ++rt) {
      const unsigned char* p = &Bs[(wr * 64 + rt * 16 + l16) * DN];
      i32x4 lo = *(const i32x4*)&p[(kc * 8 + ((quad * 2 + 0) ^ r7)) * 16];
      i32x4 hi = *(const i32x4*)&p[(kc * 8 + ((quad * 2 + 1) ^ r7)) * 16];
      afr[kc][rt][0] = lo[0]; afr[kc][rt][1] = lo[1];
      afr[kc][rt][2] = lo[2]; afr[kc][rt][3] = lo[3];
      afr[kc][rt][4] = hi[0]; afr[kc][rt][5] = hi[1];
      afr[kc][rt][6] = hi[2]; afr[kc][rt][7] = hi[3];
    }
  __syncthreads();  // afr reads done; LDS free for B staging

  // B staging source offsets: 6 issues/thread per 64-row tile
  int srcoff[6];
#pragma unroll
  for (int i = 0; i < 6; ++i) {
    const int ci = i * 256 + tid;                 // 16B chunk 0..1535
    const int row = ci / 24;
    const int j = ci - row * 24;
    const int gj = (j & 24) | ((j ^ row) & 7);
    srcoff[i] = row * DN + gj * 16;
  }

  const unsigned char* bchunk = mn8 + (size_t)mchunk0 * DN;
  // prologue: issue tile 0 into buf 0
#pragma unroll
  for (int i = 0; i < 6; ++i)
    async16(bchunk + srcoff[i], &Bs[(i * 256 + wave * 64) * 16]);

#pragma unroll 1
  for (int mt = 0; mt < MT_PER; ++mt) {
    __syncthreads();  // buf[mt&1] staged; prior reads of buf[(mt+1)&1] done
    unsigned char* cur = &Bs[(mt & 1) * BTILE_B];
    if (mt + 1 < MT_PER) {
      unsigned char* nxt = &Bs[((mt + 1) & 1) * BTILE_B];
      const unsigned char* nb = bchunk + (size_t)(mt + 1) * BTILE_B;
#pragma unroll
      for (int i = 0; i < 6; ++i)
        async16(nb + srcoff[i], &nxt[(i * 256 + wave * 64) * 16]);
    }

    f32x4 acc[4][2];
#pragma unroll
    for (int rt = 0; rt < 4; ++rt)
#pragma unroll
      for (int ct = 0; ct < 2; ++ct) acc[rt][ct] = (f32x4){0.f, 0.f, 0.f, 0.f};

#pragma unroll
    for (int kc = 0; kc < 3; ++kc) {
      i32x8 bfr[2];
#pragma unroll
      for (int ct = 0; ct < 2; ++ct) {
        const unsigned char* p = &cur[(wc * 32 + ct * 16 + l16) * DN];
        i32x4 lo = *(const i32x4*)&p[(kc * 8 + ((quad * 2 + 0) ^ r7)) * 16];
        i32x4 hi = *(const i32x4*)&p[(kc * 8 + ((quad * 2 + 1) ^ r7)) * 16];
        bfr[ct][0] = lo[0]; bfr[ct][1] = lo[1];
        bfr[ct][2] = lo[2]; bfr[ct][3] = lo[3];
        bfr[ct][4] = hi[0]; bfr[ct][5] = hi[1];
        bfr[ct][6] = hi[2]; bfr[ct][7] = hi[3];
      }
#pragma unroll
      for (int rt = 0; rt < 4; ++rt)
#pragma unroll
        for (int ct = 0; ct < 2; ++ct)
          acc[rt][ct] = __builtin_amdgcn_mfma_scale_f32_16x16x128_f8f6f4(
              afr[kc][rt], bfr[ct], acc[rt][ct], 0, 0,  // fmtA=fp8, fmtB=fp8
              0, 0x7f7f7f7f, 0, 0x7f7f7f7f);            // scales = 1.0
    }

#pragma unroll
    for (int rt = 0; rt < 4; ++rt)
#pragma unroll
      for (int r = 0; r < 4; ++r) {
        const float v = fmaxf(acc[rt][0][r], acc[rt][1][r]);
        rmax[rt * 4 + r] = fmaxf(rmax[rt * 4 + r], v);
      }
  }

#pragma unroll
  for (int i = 0; i < 16; ++i) {
    float v = rmax[i];
    v = fmaxf(v, __shfl_xor(v, 1));
    v = fmaxf(v, __shfl_xor(v, 2));
    v = fmaxf(v, __shfl_xor(v, 4));
    v = fmaxf(v, __shfl_xor(v, 8));
    rmax[i] = v;
  }
  if (l16 == 0) {
#pragma unroll
    for (int rt = 0; rt < 4; ++rt)
#pragma unroll
      for (int r = 0; r < 4; ++r)
        smax[wc][wr * 64 + rt * 16 + quad * 4 + r] = rmax[rt * 4 + r];
  }
  __syncthreads();
  if (tid < 128) {
    const float v = fmaxf(smax[0][tid], smax[1][tid]);
    pmax[(size_t)(qrow0 + tid) * NCHUNK + blockIdx.y] = v;
  }
}

// ------- Kernel C: reduce partials; uniform row OR exact fp32 re-check -----
__global__ __launch_bounds__(256) void decide_kernel(
    const float* __restrict__ pmax, const float* __restrict__ qe,
    const float* __restrict__ me, const float* __restrict__ labels,
    float* __restrict__ out) {
  const int q = blockIdx.x;
  const int t = threadIdx.x;  // 256
  __shared__ float smx;
  if (t < 64) {
    float v = pmax[(size_t)q * NCHUNK + t];  // NCHUNK == 64
#pragma unroll
    for (int m = 1; m < 64; m <<= 1) v = fmaxf(v, __shfl_xor(v, m));
    if (t == 0) smx = v;
  }
  __syncthreads();
  if (smx <= 0.5f) {  // uniform fast path (expected for all queries)
    if (t < CN) out[(size_t)q * CN + t] = 1.0f / 128.0f;
    return;
  }
  // exact fp32 path (rare / borderline queries only)
  __shared__ float sred[256];
  __shared__ int sidx[256];
  __shared__ float wsum[4];
  const float* qr = qe + (size_t)q * DN;
  float ss = 0.f;
  for (int i = t; i < DN; i += 256) ss += qr[i] * qr[i];
#pragma unroll
  for (int m = 1; m < 64; m <<= 1) ss += __shfl_xor(ss, m);
  if ((t & 63) == 0) wsum[t >> 6] = ss;
  __syncthreads();
  const float qnorm = fmaxf(sqrtf(wsum[0] + wsum[1] + wsum[2] + wsum[3]), 1e-8f);

  float best = -3.0e38f;
  int bidx = 0x7fffffff;
  for (int j = t; j < MN; j += 256) {
    const float* mr = me + (size_t)j * DN;
    float dot = 0.f, ms = 0.f;
    for (int k = 0; k < DN; ++k) {
      float a = qr[k], b = mr[k];
      dot += a * b;
      ms += b * b;
    }
    const float sim = dot / (qnorm * fmaxf(sqrtf(ms), 1e-8f));
    if (sim > best) { best = sim; bidx = j; }  // strict > keeps first index
  }
  sred[t] = best;
  sidx[t] = bidx;
  __syncthreads();
  for (int s = 128; s > 0; s >>= 1) {
    if (t < s) {
      const float ov = sred[t + s];
      const int oi = sidx[t + s];
      if (ov > sred[t] || (ov == sred[t] && oi < sidx[t])) {
        sred[t] = ov;
        sidx[t] = oi;
      }
    }
    __syncthreads();
  }
  const float mx = sred[0];
  const int mi = sidx[0];
  if (t < CN)
    out[(size_t)q * CN + t] =
        (mx > 0.7f) ? labels[(size_t)mi * CN + t] : (1.0f / 128.0f);
}

extern "C" void kernel_launch(void* const* d_in, const int* in_sizes, int n_in,
                              void* d_out, int out_size, void* d_ws,
                              size_t ws_size, hipStream_t stream) {
  const float* qe = (const float*)d_in[0];  // [4096,384] f32
  const float* me = (const float*)d_in[1];  // [65536,384] f32
  const float* lb = (const float*)d_in[2];  // [65536,128] f32
  float* out = (float*)d_out;               // [4096,128] f32

  char* ws = (char*)d_ws;
  const size_t OFF_QN = 0;
  const size_t OFF_MN = OFF_QN + (size_t)QN * DN;        // 1,572,864
  const size_t OFF_PMAX = OFF_MN + (size_t)MN * DN;      // +25,165,824
  unsigned char* qn8 = (unsigned char*)(ws + OFF_QN);
  unsigned char* mn8 = (unsigned char*)(ws + OFF_MN);
  float* pmax = (float*)(ws + OFF_PMAX);                 // [4096][64] = 1 MB

  nrm_kernel<<<(QN + MN) / 4, 256, 0, stream>>>(qe, me, qn8, mn8);
  gemm_max_kernel<<<dim3(QN / 128, NCHUNK), 256, 0, stream>>>(qn8, mn8, pmax);
  decide_kernel<<<QN, 256, 0, stream>>>(pmax, qe, me, lb, out);
}

// Round 6
// 254.544 us; speedup vs baseline: 1.1841x; 1.1841x over previous
//
#include <hip/hip_runtime.h>
#include <math.h>

// Problem constants
#define QN 4096
#define MN 65536
#define DN 384
#define CN 128
#define NCHUNK 64                 // m-chunks (grid.y of GEMM)
#define MROWS_PER_CHUNK (MN / NCHUNK)   // 1024
#define MT_PER (MROWS_PER_CHUNK / 64)   // 16 m-tiles (64 rows) per block
#define BTILE_B (64 * DN)               // 24576 B per B tile

typedef __attribute__((ext_vector_type(8))) int i32x8;
typedef __attribute__((ext_vector_type(4))) int i32x4;
typedef __attribute__((ext_vector_type(4))) float f32x4;

// f32 -> OCP e4m3fn
__device__ __forceinline__ unsigned char f2fp8(float f) {
  return (unsigned char)(__builtin_amdgcn_cvt_pk_fp8_f32(f, 0.f, 0, false) & 0xff);
}

__device__ __forceinline__ void async16(const void* g, void* l) {
  __builtin_amdgcn_global_load_lds(
      (const __attribute__((address_space(1))) unsigned int*)g,
      (__attribute__((address_space(3))) unsigned int*)l, 16, 0, 0);
}

// ------- Kernel A: L2-normalize rows (q then m) -> fp8, one wave per row ---
__global__ __launch_bounds__(256) void nrm_kernel(const float* __restrict__ qe,
                                                  const float* __restrict__ me,
                                                  unsigned char* __restrict__ yq,
                                                  unsigned char* __restrict__ ym) {
  const int row = blockIdx.x * 4 + (threadIdx.x >> 6);
  const int lane = threadIdx.x & 63;
  const float* xr;
  unsigned char* yr;
  if (row < QN) {
    xr = qe + (size_t)row * DN;
    yr = yq + (size_t)row * DN;
  } else {
    xr = me + (size_t)(row - QN) * DN;
    yr = ym + (size_t)(row - QN) * DN;
  }
  float v[6];
  float ss = 0.f;
#pragma unroll
  for (int i = 0; i < 6; ++i) {
    v[i] = xr[lane + i * 64];
    ss += v[i] * v[i];
  }
#pragma unroll
  for (int m = 1; m < 64; m <<= 1) ss += __shfl_xor(ss, m);
  const float scale = 1.0f / fmaxf(sqrtf(ss), 1e-8f);
#pragma unroll
  for (int i = 0; i < 6; ++i) yr[lane + i * 64] = f2fp8(v[i] * scale);
}

// ------- Kernel B: MX-fp8 GEMM, reg-hoisted A + double-buffered B ---------
// Single-barrier pipeline per 64-row B tile:
//   barrier; issue async B(mt+1) -> buf[!cur]; compute(mt) from buf[cur]
// min-waves kept at 2 (NOT 3): R5 showed launch_bounds(256,3) caps VGPR at
// ~170 and spills ~21 regs of the 96-VGPR afr array (WRITE_SIZE 2.8->44 MB,
// MfmaUtil 44->30). 256-VGPR budget holds afr spill-free (R4-verified).
__global__ __launch_bounds__(256, 2) void gemm_max_kernel(
    const unsigned char* __restrict__ qn8, const unsigned char* __restrict__ mn8,
    float* __restrict__ pmax) {
  __shared__ unsigned char Bs[2 * BTILE_B];  // 48 KB (also holds A initially)
  __shared__ float smax[2][128];

  const int tid = threadIdx.x;
  const int wave = tid >> 6, lane = tid & 63;
  const int wr = wave >> 1, wc = wave & 1;   // waves: 2x2 over 128q x 64m
  const int quad = lane >> 4, l16 = lane & 15;
  const int r7 = l16 & 7;
  const int qrow0 = blockIdx.x * 128;
  const int mchunk0 = blockIdx.y * MROWS_PER_CHUNK;

  float rmax[16];
#pragma unroll
  for (int i = 0; i < 16; ++i) rmax[i] = -3.0e38f;

  // ---- stage A tile (128x384 = 48 KB) once, hoist fragments to registers --
  {
    const unsigned char* abase = qn8 + (size_t)qrow0 * DN;
#pragma unroll
    for (int i = 0; i < 12; ++i) {
      const int ci = i * 256 + tid;               // 16B chunk 0..3071
      const int row = ci / 24;
      const int j = ci - row * 24;
      const int gj = (j & 24) | ((j ^ row) & 7);  // XOR-swizzled source chunk
      async16(abase + row * DN + gj * 16, &Bs[(i * 256 + wave * 64) * 16]);
    }
  }
  __syncthreads();
  i32x8 afr[3][4];
#pragma unroll
  for (int kc = 0; kc < 3; ++kc)
#pragma unroll
    for (int rt = 0; rt < 4; ++rt) {
      const unsigned char* p = &Bs[(wr * 64 + rt * 16 + l16) * DN];
      i32x4 lo = *(const i32x4*)&p[(kc * 8 + ((quad * 2 + 0) ^ r7)) * 16];
      i32x4 hi = *(const i32x4*)&p[(kc * 8 + ((quad * 2 + 1) ^ r7)) * 16];
      afr[kc][rt][0] = lo[0]; afr[kc][rt][1] = lo[1];
      afr[kc][rt][2] = lo[2]; afr[kc][rt][3] = lo[3];
      afr[kc][rt][4] = hi[0]; afr[kc][rt][5] = hi[1];
      afr[kc][rt][6] = hi[2]; afr[kc][rt][7] = hi[3];
    }
  __syncthreads();  // afr reads done; LDS free for B staging

  // B staging source offsets: 6 issues/thread per 64-row tile
  int srcoff[6];
#pragma unroll
  for (int i = 0; i < 6; ++i) {
    const int ci = i * 256 + tid;                 // 16B chunk 0..1535
    const int row = ci / 24;
    const int j = ci - row * 24;
    const int gj = (j & 24) | ((j ^ row) & 7);
    srcoff[i] = row * DN + gj * 16;
  }

  const unsigned char* bchunk = mn8 + (size_t)mchunk0 * DN;
  // prologue: issue tile 0 into buf 0
#pragma unroll
  for (int i = 0; i < 6; ++i)
    async16(bchunk + srcoff[i], &Bs[(i * 256 + wave * 64) * 16]);

#pragma unroll 1
  for (int mt = 0; mt < MT_PER; ++mt) {
    __syncthreads();  // buf[mt&1] staged; prior reads of buf[(mt+1)&1] done
    unsigned char* cur = &Bs[(mt & 1) * BTILE_B];
    if (mt + 1 < MT_PER) {
      unsigned char* nxt = &Bs[((mt + 1) & 1) * BTILE_B];
      const unsigned char* nb = bchunk + (size_t)(mt + 1) * BTILE_B;
#pragma unroll
      for (int i = 0; i < 6; ++i)
        async16(nb + srcoff[i], &nxt[(i * 256 + wave * 64) * 16]);
    }

    f32x4 acc[4][2];
#pragma unroll
    for (int rt = 0; rt < 4; ++rt)
#pragma unroll
      for (int ct = 0; ct < 2; ++ct) acc[rt][ct] = (f32x4){0.f, 0.f, 0.f, 0.f};

#pragma unroll
    for (int kc = 0; kc < 3; ++kc) {
      i32x8 bfr[2];
#pragma unroll
      for (int ct = 0; ct < 2; ++ct) {
        const unsigned char* p = &cur[(wc * 32 + ct * 16 + l16) * DN];
        i32x4 lo = *(const i32x4*)&p[(kc * 8 + ((quad * 2 + 0) ^ r7)) * 16];
        i32x4 hi = *(const i32x4*)&p[(kc * 8 + ((quad * 2 + 1) ^ r7)) * 16];
        bfr[ct][0] = lo[0]; bfr[ct][1] = lo[1];
        bfr[ct][2] = lo[2]; bfr[ct][3] = lo[3];
        bfr[ct][4] = hi[0]; bfr[ct][5] = hi[1];
        bfr[ct][6] = hi[2]; bfr[ct][7] = hi[3];
      }
#pragma unroll
      for (int rt = 0; rt < 4; ++rt)
#pragma unroll
        for (int ct = 0; ct < 2; ++ct)
          acc[rt][ct] = __builtin_amdgcn_mfma_scale_f32_16x16x128_f8f6f4(
              afr[kc][rt], bfr[ct], acc[rt][ct], 0, 0,  // fmtA=fp8, fmtB=fp8
              0, 0x7f7f7f7f, 0, 0x7f7f7f7f);            // scales = 1.0
    }

#pragma unroll
    for (int rt = 0; rt < 4; ++rt)
#pragma unroll
      for (int r = 0; r < 4; ++r) {
        const float v = fmaxf(acc[rt][0][r], acc[rt][1][r]);
        rmax[rt * 4 + r] = fmaxf(rmax[rt * 4 + r], v);
      }
  }

#pragma unroll
  for (int i = 0; i < 16; ++i) {
    float v = rmax[i];
    v = fmaxf(v, __shfl_xor(v, 1));
    v = fmaxf(v, __shfl_xor(v, 2));
    v = fmaxf(v, __shfl_xor(v, 4));
    v = fmaxf(v, __shfl_xor(v, 8));
    rmax[i] = v;
  }
  if (l16 == 0) {
#pragma unroll
    for (int rt = 0; rt < 4; ++rt)
#pragma unroll
      for (int r = 0; r < 4; ++r)
        smax[wc][wr * 64 + rt * 16 + quad * 4 + r] = rmax[rt * 4 + r];
  }
  __syncthreads();
  if (tid < 128) {
    const float v = fmaxf(smax[0][tid], smax[1][tid]);
    pmax[(size_t)(qrow0 + tid) * NCHUNK + blockIdx.y] = v;
  }
}

// ------- Kernel C: reduce partials; uniform row OR exact fp32 re-check -----
__global__ __launch_bounds__(256) void decide_kernel(
    const float* __restrict__ pmax, const float* __restrict__ qe,
    const float* __restrict__ me, const float* __restrict__ labels,
    float* __restrict__ out) {
  const int q = blockIdx.x;
  const int t = threadIdx.x;  // 256
  __shared__ float smx;
  if (t < 64) {
    float v = pmax[(size_t)q * NCHUNK + t];  // NCHUNK == 64
#pragma unroll
    for (int m = 1; m < 64; m <<= 1) v = fmaxf(v, __shfl_xor(v, m));
    if (t == 0) smx = v;
  }
  __syncthreads();
  if (smx <= 0.5f) {  // uniform fast path (expected for all queries)
    if (t < CN) out[(size_t)q * CN + t] = 1.0f / 128.0f;
    return;
  }
  // exact fp32 path (rare / borderline queries only)
  __shared__ float sred[256];
  __shared__ int sidx[256];
  __shared__ float wsum[4];
  const float* qr = qe + (size_t)q * DN;
  float ss = 0.f;
  for (int i = t; i < DN; i += 256) ss += qr[i] * qr[i];
#pragma unroll
  for (int m = 1; m < 64; m <<= 1) ss += __shfl_xor(ss, m);
  if ((t & 63) == 0) wsum[t >> 6] = ss;
  __syncthreads();
  const float qnorm = fmaxf(sqrtf(wsum[0] + wsum[1] + wsum[2] + wsum[3]), 1e-8f);

  float best = -3.0e38f;
  int bidx = 0x7fffffff;
  for (int j = t; j < MN; j += 256) {
    const float* mr = me + (size_t)j * DN;
    float dot = 0.f, ms = 0.f;
    for (int k = 0; k < DN; ++k) {
      float a = qr[k], b = mr[k];
      dot += a * b;
      ms += b * b;
    }
    const float sim = dot / (qnorm * fmaxf(sqrtf(ms), 1e-8f));
    if (sim > best) { best = sim; bidx = j; }  // strict > keeps first index
  }
  sred[t] = best;
  sidx[t] = bidx;
  __syncthreads();
  for (int s = 128; s > 0; s >>= 1) {
    if (t < s) {
      const float ov = sred[t + s];
      const int oi = sidx[t + s];
      if (ov > sred[t] || (ov == sred[t] && oi < sidx[t])) {
        sred[t] = ov;
        sidx[t] = oi;
      }
    }
    __syncthreads();
  }
  const float mx = sred[0];
  const int mi = sidx[0];
  if (t < CN)
    out[(size_t)q * CN + t] =
        (mx > 0.7f) ? labels[(size_t)mi * CN + t] : (1.0f / 128.0f);
}

extern "C" void kernel_launch(void* const* d_in, const int* in_sizes, int n_in,
                              void* d_out, int out_size, void* d_ws,
                              size_t ws_size, hipStream_t stream) {
  const float* qe = (const float*)d_in[0];  // [4096,384] f32
  const float* me = (const float*)d_in[1];  // [65536,384] f32
  const float* lb = (const float*)d_in[2];  // [65536,128] f32
  float* out = (float*)d_out;               // [4096,128] f32

  char* ws = (char*)d_ws;
  const size_t OFF_QN = 0;
  const size_t OFF_MN = OFF_QN + (size_t)QN * DN;        // 1,572,864
  const size_t OFF_PMAX = OFF_MN + (size_t)MN * DN;      // +25,165,824
  unsigned char* qn8 = (unsigned char*)(ws + OFF_QN);
  unsigned char* mn8 = (unsigned char*)(ws + OFF_MN);
  float* pmax = (float*)(ws + OFF_PMAX);                 // [4096][64] = 1 MB

  nrm_kernel<<<(QN + MN) / 4, 256, 0, stream>>>(qe, me, qn8, mn8);
  gemm_max_kernel<<<dim3(QN / 128, NCHUNK), 256, 0, stream>>>(qn8, mn8, pmax);
  decide_kernel<<<QN, 256, 0, stream>>>(pmax, qe, me, lb, out);
}

// Round 7
// 254.056 us; speedup vs baseline: 1.1864x; 1.0019x over previous
//
#include <hip/hip_runtime.h>
#include <math.h>

// Problem constants
#define QN 4096
#define MN 65536
#define DN 384
#define CN 128
#define NCHUNK 64                 // m-chunks (grid.y of GEMM)
#define MROWS_PER_CHUNK (MN / NCHUNK)   // 1024
#define MT_PER (MROWS_PER_CHUNK / 64)   // 16 m-tiles (64 rows) per block
#define BTILE_B (64 * DN)               // 24576 B per B tile

typedef __attribute__((ext_vector_type(8))) int i32x8;
typedef __attribute__((ext_vector_type(4))) int i32x4;
typedef __attribute__((ext_vector_type(4))) float f32x4;

// f32 -> OCP e4m3fn
__device__ __forceinline__ unsigned char f2fp8(float f) {
  return (unsigned char)(__builtin_amdgcn_cvt_pk_fp8_f32(f, 0.f, 0, false) & 0xff);
}

__device__ __forceinline__ void async16(const void* g, void* l) {
  __builtin_amdgcn_global_load_lds(
      (const __attribute__((address_space(1))) unsigned int*)g,
      (__attribute__((address_space(3))) unsigned int*)l, 16, 0, 0);
}

// ------- Kernel A: L2-normalize rows (q then m) -> fp8, one wave per row ---
__global__ __launch_bounds__(256) void nrm_kernel(const float* __restrict__ qe,
                                                  const float* __restrict__ me,
                                                  unsigned char* __restrict__ yq,
                                                  unsigned char* __restrict__ ym) {
  const int row = blockIdx.x * 4 + (threadIdx.x >> 6);
  const int lane = threadIdx.x & 63;
  const float* xr;
  unsigned char* yr;
  if (row < QN) {
    xr = qe + (size_t)row * DN;
    yr = yq + (size_t)row * DN;
  } else {
    xr = me + (size_t)(row - QN) * DN;
    yr = ym + (size_t)(row - QN) * DN;
  }
  float v[6];
  float ss = 0.f;
#pragma unroll
  for (int i = 0; i < 6; ++i) {
    v[i] = xr[lane + i * 64];
    ss += v[i] * v[i];
  }
#pragma unroll
  for (int m = 1; m < 64; m <<= 1) ss += __shfl_xor(ss, m);
  const float scale = 1.0f / fmaxf(sqrtf(ss), 1e-8f);
#pragma unroll
  for (int i = 0; i < 6; ++i) yr[lane + i * 64] = f2fp8(v[i] * scale);
}

// ------- Kernel B: MX-fp8 GEMM, reg-hoisted A + double-buffered B ---------
// Single-barrier pipeline per 64-row B tile, PLUS register-level software
// pipelining of the B fragments inside the kc loop: bfr(kc+1) ds_reads issue
// while MFMA(kc) occupies the matrix pipe, so their lgkmcnt wait is hidden.
// R6 evidence: MfmaUtil 45.6% == serialized 3x(ds_wait+8 MFMA) model; this
// targets that serialization directly.
// min-waves 2 (NOT 3): launch_bounds(256,3) spills afr (R5: WRITE 44 MB).
__global__ __launch_bounds__(256, 2) void gemm_max_kernel(
    const unsigned char* __restrict__ qn8, const unsigned char* __restrict__ mn8,
    float* __restrict__ pmax) {
  __shared__ unsigned char Bs[2 * BTILE_B];  // 48 KB (also holds A initially)
  __shared__ float smax[2][128];

  const int tid = threadIdx.x;
  const int wave = tid >> 6, lane = tid & 63;
  const int wr = wave >> 1, wc = wave & 1;   // waves: 2x2 over 128q x 64m
  const int quad = lane >> 4, l16 = lane & 15;
  const int r7 = l16 & 7;
  const int qrow0 = blockIdx.x * 128;
  const int mchunk0 = blockIdx.y * MROWS_PER_CHUNK;

  float rmax[16];
#pragma unroll
  for (int i = 0; i < 16; ++i) rmax[i] = -3.0e38f;

  // ---- stage A tile (128x384 = 48 KB) once, hoist fragments to registers --
  {
    const unsigned char* abase = qn8 + (size_t)qrow0 * DN;
#pragma unroll
    for (int i = 0; i < 12; ++i) {
      const int ci = i * 256 + tid;               // 16B chunk 0..3071
      const int row = ci / 24;
      const int j = ci - row * 24;
      const int gj = (j & 24) | ((j ^ row) & 7);  // XOR-swizzled source chunk
      async16(abase + row * DN + gj * 16, &Bs[(i * 256 + wave * 64) * 16]);
    }
  }
  __syncthreads();
  i32x8 afr[3][4];
#pragma unroll
  for (int kc = 0; kc < 3; ++kc)
#pragma unroll
    for (int rt = 0; rt < 4; ++rt) {
      const unsigned char* p = &Bs[(wr * 64 + rt * 16 + l16) * DN];
      i32x4 lo = *(const i32x4*)&p[(kc * 8 + ((quad * 2 + 0) ^ r7)) * 16];
      i32x4 hi = *(const i32x4*)&p[(kc * 8 + ((quad * 2 + 1) ^ r7)) * 16];
      afr[kc][rt][0] = lo[0]; afr[kc][rt][1] = lo[1];
      afr[kc][rt][2] = lo[2]; afr[kc][rt][3] = lo[3];
      afr[kc][rt][4] = hi[0]; afr[kc][rt][5] = hi[1];
      afr[kc][rt][6] = hi[2]; afr[kc][rt][7] = hi[3];
    }
  __syncthreads();  // afr reads done; LDS free for B staging

  // B staging source offsets: 6 issues/thread per 64-row tile
  int srcoff[6];
#pragma unroll
  for (int i = 0; i < 6; ++i) {
    const int ci = i * 256 + tid;                 // 16B chunk 0..1535
    const int row = ci / 24;
    const int j = ci - row * 24;
    const int gj = (j & 24) | ((j ^ row) & 7);
    srcoff[i] = row * DN + gj * 16;
  }

  const unsigned char* bchunk = mn8 + (size_t)mchunk0 * DN;
  // prologue: issue tile 0 into buf 0
#pragma unroll
  for (int i = 0; i < 6; ++i)
    async16(bchunk + srcoff[i], &Bs[(i * 256 + wave * 64) * 16]);

  // fragment read offsets (bytes) within a B row, swizzled
  const int c_lo = ((quad * 2 + 0) ^ r7) * 16;
  const int c_hi = ((quad * 2 + 1) ^ r7) * 16;

#pragma unroll 1
  for (int mt = 0; mt < MT_PER; ++mt) {
    __syncthreads();  // buf[mt&1] staged; prior reads of buf[(mt+1)&1] done
    const unsigned char* cur = &Bs[(mt & 1) * BTILE_B];
    if (mt + 1 < MT_PER) {
      unsigned char* nxt = &Bs[((mt + 1) & 1) * BTILE_B];
      const unsigned char* nb = bchunk + (size_t)(mt + 1) * BTILE_B;
#pragma unroll
      for (int i = 0; i < 6; ++i)
        async16(nb + srcoff[i], &nxt[(i * 256 + wave * 64) * 16]);
    }

    f32x4 acc[4][2];
#pragma unroll
    for (int rt = 0; rt < 4; ++rt)
#pragma unroll
      for (int ct = 0; ct < 2; ++ct) acc[rt][ct] = (f32x4){0.f, 0.f, 0.f, 0.f};

    // --- register-double-buffered bfr: load kc+1 under MFMA(kc) ---
    i32x8 bfr[2][2];
#pragma unroll
    for (int ct = 0; ct < 2; ++ct) {
      const unsigned char* p = &cur[(wc * 32 + ct * 16 + l16) * DN];
      i32x4 lo = *(const i32x4*)&p[c_lo];
      i32x4 hi = *(const i32x4*)&p[c_hi];
      bfr[0][ct][0] = lo[0]; bfr[0][ct][1] = lo[1];
      bfr[0][ct][2] = lo[2]; bfr[0][ct][3] = lo[3];
      bfr[0][ct][4] = hi[0]; bfr[0][ct][5] = hi[1];
      bfr[0][ct][6] = hi[2]; bfr[0][ct][7] = hi[3];
    }
#pragma unroll
    for (int kc = 0; kc < 3; ++kc) {
      const int pb = kc & 1;
      if (kc < 2) {
#pragma unroll
        for (int ct = 0; ct < 2; ++ct) {
          const unsigned char* p =
              &cur[(wc * 32 + ct * 16 + l16) * DN + (kc + 1) * 128];
          i32x4 lo = *(const i32x4*)&p[c_lo];
          i32x4 hi = *(const i32x4*)&p[c_hi];
          bfr[pb ^ 1][ct][0] = lo[0]; bfr[pb ^ 1][ct][1] = lo[1];
          bfr[pb ^ 1][ct][2] = lo[2]; bfr[pb ^ 1][ct][3] = lo[3];
          bfr[pb ^ 1][ct][4] = hi[0]; bfr[pb ^ 1][ct][5] = hi[1];
          bfr[pb ^ 1][ct][6] = hi[2]; bfr[pb ^ 1][ct][7] = hi[3];
        }
      }
#pragma unroll
      for (int rt = 0; rt < 4; ++rt)
#pragma unroll
        for (int ct = 0; ct < 2; ++ct)
          acc[rt][ct] = __builtin_amdgcn_mfma_scale_f32_16x16x128_f8f6f4(
              afr[kc][rt], bfr[pb][ct], acc[rt][ct], 0, 0,  // fmt fp8/fp8
              0, 0x7f7f7f7f, 0, 0x7f7f7f7f);                // scales = 1.0
    }

#pragma unroll
    for (int rt = 0; rt < 4; ++rt)
#pragma unroll
      for (int r = 0; r < 4; ++r) {
        const float v = fmaxf(acc[rt][0][r], acc[rt][1][r]);
        rmax[rt * 4 + r] = fmaxf(rmax[rt * 4 + r], v);
      }
  }

#pragma unroll
  for (int i = 0; i < 16; ++i) {
    float v = rmax[i];
    v = fmaxf(v, __shfl_xor(v, 1));
    v = fmaxf(v, __shfl_xor(v, 2));
    v = fmaxf(v, __shfl_xor(v, 4));
    v = fmaxf(v, __shfl_xor(v, 8));
    rmax[i] = v;
  }
  if (l16 == 0) {
#pragma unroll
    for (int rt = 0; rt < 4; ++rt)
#pragma unroll
      for (int r = 0; r < 4; ++r)
        smax[wc][wr * 64 + rt * 16 + quad * 4 + r] = rmax[rt * 4 + r];
  }
  __syncthreads();
  if (tid < 128) {
    const float v = fmaxf(smax[0][tid], smax[1][tid]);
    pmax[(size_t)(qrow0 + tid) * NCHUNK + blockIdx.y] = v;
  }
}

// ------- Kernel C: reduce partials; uniform row OR exact fp32 re-check -----
__global__ __launch_bounds__(256) void decide_kernel(
    const float* __restrict__ pmax, const float* __restrict__ qe,
    const float* __restrict__ me, const float* __restrict__ labels,
    float* __restrict__ out) {
  const int q = blockIdx.x;
  const int t = threadIdx.x;  // 256
  __shared__ float smx;
  if (t < 64) {
    float v = pmax[(size_t)q * NCHUNK + t];  // NCHUNK == 64
#pragma unroll
    for (int m = 1; m < 64; m <<= 1) v = fmaxf(v, __shfl_xor(v, m));
    if (t == 0) smx = v;
  }
  __syncthreads();
  if (smx <= 0.5f) {  // uniform fast path (expected for all queries)
    if (t < CN) out[(size_t)q * CN + t] = 1.0f / 128.0f;
    return;
  }
  // exact fp32 path (rare / borderline queries only)
  __shared__ float sred[256];
  __shared__ int sidx[256];
  __shared__ float wsum[4];
  const float* qr = qe + (size_t)q * DN;
  float ss = 0.f;
  for (int i = t; i < DN; i += 256) ss += qr[i] * qr[i];
#pragma unroll
  for (int m = 1; m < 64; m <<= 1) ss += __shfl_xor(ss, m);
  if ((t & 63) == 0) wsum[t >> 6] = ss;
  __syncthreads();
  const float qnorm = fmaxf(sqrtf(wsum[0] + wsum[1] + wsum[2] + wsum[3]), 1e-8f);

  float best = -3.0e38f;
  int bidx = 0x7fffffff;
  for (int j = t; j < MN; j += 256) {
    const float* mr = me + (size_t)j * DN;
    float dot = 0.f, ms = 0.f;
    for (int k = 0; k < DN; ++k) {
      float a = qr[k], b = mr[k];
      dot += a * b;
      ms += b * b;
    }
    const float sim = dot / (qnorm * fmaxf(sqrtf(ms), 1e-8f));
    if (sim > best) { best = sim; bidx = j; }  // strict > keeps first index
  }
  sred[t] = best;
  sidx[t] = bidx;
  __syncthreads();
  for (int s = 128; s > 0; s >>= 1) {
    if (t < s) {
      const float ov = sred[t + s];
      const int oi = sidx[t + s];
      if (ov > sred[t] || (ov == sred[t] && oi < sidx[t])) {
        sred[t] = ov;
        sidx[t] = oi;
      }
    }
    __syncthreads();
  }
  const float mx = sred[0];
  const int mi = sidx[0];
  if (t < CN)
    out[(size_t)q * CN + t] =
        (mx > 0.7f) ? labels[(size_t)mi * CN + t] : (1.0f / 128.0f);
}

extern "C" void kernel_launch(void* const* d_in, const int* in_sizes, int n_in,
                              void* d_out, int out_size, void* d_ws,
                              size_t ws_size, hipStream_t stream) {
  const float* qe = (const float*)d_in[0];  // [4096,384] f32
  const float* me = (const float*)d_in[1];  // [65536,384] f32
  const float* lb = (const float*)d_in[2];  // [65536,128] f32
  float* out = (float*)d_out;               // [4096,128] f32

  char* ws = (char*)d_ws;
  const size_t OFF_QN = 0;
  const size_t OFF_MN = OFF_QN + (size_t)QN * DN;        // 1,572,864
  const size_t OFF_PMAX = OFF_MN + (size_t)MN * DN;      // +25,165,824
  unsigned char* qn8 = (unsigned char*)(ws + OFF_QN);
  unsigned char* mn8 = (unsigned char*)(ws + OFF_MN);
  float* pmax = (float*)(ws + OFF_PMAX);                 // [4096][64] = 1 MB

  nrm_kernel<<<(QN + MN) / 4, 256, 0, stream>>>(qe, me, qn8, mn8);
  gemm_max_kernel<<<dim3(QN / 128, NCHUNK), 256, 0, stream>>>(qn8, mn8, pmax);
  decide_kernel<<<QN, 256, 0, stream>>>(pmax, qe, me, lb, out);
}